// Round 7
// baseline (216.326 us; speedup 1.0000x reference)
//
#include <hip/hip_runtime.h>
#include <hip/hip_fp16.h>
#include <math.h>

#define N_NODES 50000
#define N_EDGES 800000
#define N_GRAPHS 512
#define NBKT 196                          // 256-node buckets
#define SENT N_NODES
#define EPB 2048                          // edges per binA block
#define NSEG 391                          // ceil(800000/2048)
#define CAP_C 64                          // slots per (bucket,segment); max observed ~30; pow2 for shift/mask
#define NBLK_B2 392                       // half-bucket blocks (128 nodes each)
#define CAP_SH 8192                       // sorted ints per half-bucket (worst-case sum < 6700)
#define NBLK_GM 782                       // gemm blocks (64 rows each)
#define PREP_GRID (NBLK_B2 + NBLK_GM)     // 1174
#define N_GROUPS 6272                     // 392*16 groups of 8 nodes
#define NBLK_G 1568                       // 6272/4 gather blocks
#define SLOTS_B (NSEG * CAP_C)            // 25024 slots per bucket

typedef float v2f __attribute__((ext_vector_type(2)));
typedef float f32x4 __attribute__((ext_vector_type(4)));
typedef short s16x8 __attribute__((ext_vector_type(8)));

// workspace byte offsets (256B-aligned)
#define OFF_DINV    0u                    // 50176 floats (nodes + sentinel + pad)
#define OFF_GGRP    200704u               // 6272 int2 {slot base, K loop bound}
#define OFF_CNTM    250880u               // 391*196 ints
#define OFF_GB      557568u               // 513 ints (graph boundaries)
#define OFF_TMP     559872u               // 196*391*64 uints = 19,618,816 B
#define OFF_SORTED  20178688u             // 392*8192 ints = 12,845,056 B
#define OFF_XS8_1   33023744u             // 50001*64 B fp8 (unscaled)
#define OFF_XS8_2   36224000u             // 50001*64 B fp8 (unscaled)
#define OFF_H2      39424256u             // 50000*64 fp16

__device__ __forceinline__ unsigned short f2bf(float f) {   // fp32 -> bf16 bits, RNE
    unsigned int u = __float_as_uint(f);
    u += 0x7FFFu + ((u >> 16) & 1u);
    return (unsigned short)(u >> 16);
}

// ---- binA: fixed-slot binning + graph-boundary precompute; no global atomics ----
__global__ __launch_bounds__(256) void binA(const int* __restrict__ src, const int* __restrict__ dst,
                                            const int* __restrict__ batch,
                                            int* __restrict__ cntmat, unsigned int* __restrict__ tmp,
                                            unsigned int* __restrict__ x1, unsigned int* __restrict__ x2,
                                            float* __restrict__ dinv, int* __restrict__ gbound) {
    __shared__ int cnt[256];
    int t = threadIdx.x;
    cnt[t] = 0;
    if (blockIdx.x == 0) {                 // zero fp8 sentinel rows + dinv sentinel
        if (t < 16) x1[N_NODES * 16 + t] = 0;
        else if (t < 32) x2[N_NODES * 16 + (t - 16)] = 0;
        else if (t == 32) dinv[SENT] = 0.0f;
    }
    if (blockIdx.x < 25) {                 // graph boundaries: gbound[g] = first idx with batch >= g
        int i0 = blockIdx.x * 2048;
#pragma unroll
        for (int it = 0; it < 8; ++it) {
            int i = i0 + it * 256 + t;
            if (i < N_NODES) {
                int b0 = batch[i];
                int b1 = (i + 1 < N_NODES) ? batch[i + 1] : N_GRAPHS;
                for (int g = b0 + 1; g <= b1; ++g) gbound[g] = i + 1;
                if (i == 0)
                    for (int g = 0; g <= b0; ++g) gbound[g] = 0;
            }
        }
    }
    __syncthreads();
    int e0 = blockIdx.x * EPB;
#pragma unroll
    for (int i = 0; i < 8; ++i) {
        int e = e0 + i * 256 + t;
        if (e < N_EDGES) {
            int s = src[e], d = dst[e];
            int b = d >> 8;
            int p = atomicAdd(&cnt[b], 1);
            tmp[((b * NSEG + blockIdx.x) << 6) + p] =
                (unsigned int)s | ((unsigned int)(d & 255) << 17);   // src < 2^17
        }
    }
    __syncthreads();
    if (t < NBKT) cntmat[blockIdx.x * NBKT + t] = cnt[t];
}

// ---- prep: heterogeneous grid. blocks [0,392): binB2 half-bucket CSR build
//      (flattened coalesced slot streams). blocks [392,1174): bf16-MFMA gemm1. ----
__global__ __launch_bounds__(256) void prep(const unsigned int* __restrict__ tmp,
                                            const int* __restrict__ cntmat,
                                            int* __restrict__ sorted, int2* __restrict__ ggrp,
                                            float* __restrict__ dinv,
                                            const float* __restrict__ X, const float* __restrict__ W1,
                                            unsigned int* __restrict__ xs8) {
    __shared__ __align__(16) char pool[36352];
    int t = threadIdx.x;

    if (blockIdx.x < NBLK_B2) {
        // ---------------- binB2 half-bucket, flattened streaming passes ----------------
        int* cnt  = (int*)pool;              // 128
        int* lbs  = (int*)(pool + 512);      // 128
        int* cur  = (int*)(pool + 1024);     // 128
        int* gK   = (int*)(pool + 1536);     // 16
        int* gpre = (int*)(pool + 1600);     // 17
        int* cseg = (int*)(pool + 1792);     // 391
        int* ldsS = (int*)(pool + 3584);     // 8192 ints
        int b2 = blockIdx.x, bkt = b2 >> 1, half = b2 & 1;
        if (t < 128) cnt[t] = 0;
        for (int i = t; i < NSEG; i += 256) cseg[i] = cntmat[i * NBKT + bkt];
        __syncthreads();
        const unsigned int* tp = tmp + bkt * SLOTS_B;
        // pass A: coalesced slot stream, count degrees of my 128 nodes
        for (int i = t; i < SLOTS_B; i += 256) {
            unsigned int pk = tp[i];                 // unconditional coalesced load
            if ((i & 63) < cseg[i >> 6]) {
                int d = (int)(pk >> 17);
                if ((d >> 7) == half) atomicAdd(&cnt[d & 127], 1);
            }
        }
        __syncthreads();
        int node = 0, deg = 0, K = 0, KP = 0, lb = 0, myreal = 0;
        if (t < 128) {
            node = bkt * 256 + half * 128 + t;
            myreal = node < N_NODES;
            deg = cnt[t];
            int count = myreal ? deg + 1 : 0;        // +1 self loop
            int mx = count;
            mx = max(mx, __shfl_xor(mx, 1));
            mx = max(mx, __shfl_xor(mx, 2));
            mx = max(mx, __shfl_xor(mx, 4));
            K = (mx + 3) & ~3;                       // group loop bound (mult of 4)
            KP = K + 4;                              // +extra quad: guard-free prefetch
            if ((t & 7) == 0) gK[t >> 3] = KP;
        }
        __syncthreads();
        if (t == 0) {
            int s = 0;
#pragma unroll
            for (int g = 0; g < 16; ++g) { gpre[g] = s; s += gK[g]; }
            gpre[16] = s;
        }
        __syncthreads();
        if (t < 128) {
            lb = 8 * gpre[t >> 3] + (t & 7);
            lbs[t] = lb;
            cur[t] = myreal ? 1 : 0;
            if (myreal) {
                dinv[node] = rsqrtf(1.0f + (float)deg);
                ldsS[lb] = node;                     // self loop at entry 0
            }
            if ((t & 7) == 0)
                ggrp[b2 * 16 + (t >> 3)] = make_int2(b2 * CAP_SH + 8 * gpre[t >> 3], K);
        }
        __syncthreads();
        // pass B: coalesced slot stream, scatter into LDS CSR
        for (int i = t; i < SLOTS_B; i += 256) {
            unsigned int pk = tp[i];
            if ((i & 63) < cseg[i >> 6]) {
                int d = (int)(pk >> 17);
                if ((d >> 7) == half) {
                    int loc = d & 127;
                    int j = atomicAdd(&cur[loc], 1);
                    ldsS[lbs[loc] + j * 8] = (int)(pk & 0x1FFFFu);
                }
            }
        }
        __syncthreads();
        if (t < 128)
            for (int j = cur[t]; j < KP; ++j) ldsS[lb + j * 8] = SENT;
        __syncthreads();
        int ptot = 8 * gpre[16];
        int4* dst4 = (int4*)(sorted + b2 * CAP_SH);
        const int4* src4 = (const int4*)ldsS;
        for (int p = t; p < (ptot >> 2); p += 256) dst4[p] = src4[p];
    } else {
        // ---- gemm1: 64 rows/block, mfma_f32_16x16x32_bf16 (HW-verified r2-r6) ----
        short* W1T = (short*)pool;               // [64 cols][136] bf16 bits
        float* sD  = (float*)(pool + 17408);     // [64 rows][68]
        int gb = blockIdx.x - NBLK_B2;
        int row0 = gb * 64;
        for (int i = t; i < 8192; i += 256) {    // stage W1 transposed to bf16
            int k = i >> 6, c = i & 63;
            W1T[c * 136 + k] = (short)f2bf(W1[i]);
        }
        __syncthreads();
        int w = t >> 6, lane = t & 63;
        int arow = lane & 15, kg = lane >> 4;    // arow = A-row = B-col; kg = k-group
        int r = row0 + w * 16 + arow;
        const float* xp = X + r * 128 + kg * 8;
        bool vr = (r < N_NODES);
        const short* wb = &W1T[arow * 136 + kg * 8];
        f32x4 ac0 = {0.f, 0.f, 0.f, 0.f}, ac1 = ac0, ac2 = ac0, ac3 = ac0;
#pragma unroll
        for (int kk = 0; kk < 4; ++kk) {
            float4 xa, xb;
            if (vr) { xa = *(const float4*)(xp); xb = *(const float4*)(xp + 4); }
            else    { xa = make_float4(0.f, 0.f, 0.f, 0.f); xb = xa; }
            xp += 32;
            s16x8 af;
            af[0] = (short)f2bf(xa.x); af[1] = (short)f2bf(xa.y);
            af[2] = (short)f2bf(xa.z); af[3] = (short)f2bf(xa.w);
            af[4] = (short)f2bf(xb.x); af[5] = (short)f2bf(xb.y);
            af[6] = (short)f2bf(xb.z); af[7] = (short)f2bf(xb.w);
            const short* wk = wb + kk * 32;
            s16x8 bf0 = *(const s16x8*)(wk);
            s16x8 bf1 = *(const s16x8*)(wk + 16 * 136);
            s16x8 bf2 = *(const s16x8*)(wk + 32 * 136);
            s16x8 bf3 = *(const s16x8*)(wk + 48 * 136);
            asm volatile(
                "s_nop 1\n\t"
                "v_mfma_f32_16x16x32_bf16 %0, %4, %5, %0\n\t"
                "v_mfma_f32_16x16x32_bf16 %1, %4, %6, %1\n\t"
                "v_mfma_f32_16x16x32_bf16 %2, %4, %7, %2\n\t"
                "v_mfma_f32_16x16x32_bf16 %3, %4, %8, %3"
                : "+v"(ac0), "+v"(ac1), "+v"(ac2), "+v"(ac3)
                : "v"(af), "v"(bf0), "v"(bf1), "v"(bf2), "v"(bf3));
        }
        asm volatile("s_nop 7\n\ts_nop 7");      // MFMA->VALU read hazard pad
        int dr = w * 16 + kg * 4;                // D row = (lane>>4)*4+reg; col = lane&15
#pragma unroll
        for (int reg = 0; reg < 4; ++reg) {
            sD[(dr + reg) * 68 + arow]      = ac0[reg];
            sD[(dr + reg) * 68 + 16 + arow] = ac1[reg];
            sD[(dr + reg) * 68 + 32 + arow] = ac2[reg];
            sD[(dr + reg) * 68 + 48 + arow] = ac3[reg];
        }
        __syncthreads();
        for (int i = t; i < 1024; i += 256) {    // quantize fp8 (unscaled)
            int lr = i >> 4, q = i & 15;
            int nd = row0 + lr;
            if (nd < N_NODES) {
                float4 v = *(const float4*)&sD[lr * 68 + q * 4];
                unsigned int pk = 0;
                pk = __builtin_amdgcn_cvt_pk_fp8_f32(v.x, v.y, pk, false);
                pk = __builtin_amdgcn_cvt_pk_fp8_f32(v.z, v.w, pk, true);
                xs8[nd * 16 + q] = pk;
            }
        }
    }
}

// ---- fp8-row accumulate with per-source dinv scale (unscaled input) ----
#define FMA_ROW(rv, ds) { \
    v2f f0 = __builtin_amdgcn_cvt_pk_f32_fp8((rv).x, false); \
    v2f f1 = __builtin_amdgcn_cvt_pk_f32_fp8((rv).x, true); \
    v2f f2 = __builtin_amdgcn_cvt_pk_f32_fp8((rv).y, false); \
    v2f f3 = __builtin_amdgcn_cvt_pk_f32_fp8((rv).y, true); \
    a0 += f0.x * (ds); a1 += f0.y * (ds); a2 += f1.x * (ds); a3 += f1.y * (ds); \
    a4 += f2.x * (ds); a5 += f2.y * (ds); a6 += f3.x * (ds); a7 += f3.y * (ds); }

// ---- gather layer 1 + fused W2 GEMM; epilogue emits xs8_2 (unscaled) ----
__global__ __launch_bounds__(256) void gather_fuse(const unsigned char* __restrict__ xs8,
                                                   const int2* __restrict__ ggrp,
                                                   const int* __restrict__ sorted,
                                                   const float* __restrict__ dinv,
                                                   const float* __restrict__ bias,
                                                   const float* __restrict__ W2,
                                                   unsigned int* __restrict__ xs8o) {
    __shared__ float sW2[64 * 64];
    __shared__ float sH[32][68];
    {
        const float4* ws = (const float4*)W2;
        float4* wd = (float4*)sW2;
        for (int i = threadIdx.x; i < 1024; i += 256) wd[i] = ws[i];
    }
    int wvl = threadIdx.x >> 6;
    int grp = blockIdx.x * 4 + wvl;

    int lane = threadIdx.x & 63;
    int sub = lane >> 3, frag = lane & 7;
    int node = grp * 8 + sub;
    int2 gi = ggrp[grp];
    int K = gi.y;
    const int* sp = sorted + gi.x + sub;
    const uint2* xr = (const uint2*)xs8 + frag;
    float a0 = 0, a1 = 0, a2 = 0, a3 = 0, a4 = 0, a5 = 0, a6 = 0, a7 = 0;
    int i0 = sp[0], i1 = sp[8], i2 = sp[16], i3 = sp[24];
    for (int k = 0; k < K; k += 4) {
        uint2 r0 = xr[i0 * 8];
        uint2 r1 = xr[i1 * 8];
        uint2 r2 = xr[i2 * 8];
        uint2 r3 = xr[i3 * 8];
        float s0 = dinv[i0], s1 = dinv[i1], s2 = dinv[i2], s3 = dinv[i3];
        const int* np = sp + (k + 4) * 8;
        i0 = np[0]; i1 = np[8]; i2 = np[16]; i3 = np[24];
        FMA_ROW(r0, s0); FMA_ROW(r1, s1); FMA_ROW(r2, s2); FMA_ROW(r3, s3);
    }
    {
        float dv = dinv[node];
        float4 bA = *(const float4*)(bias + frag * 8);
        float4 bB = *(const float4*)(bias + frag * 8 + 4);
        float4 w0, w1;
        w0.x = fmaxf(a0 * dv + bA.x, 0.0f); w0.y = fmaxf(a1 * dv + bA.y, 0.0f);
        w0.z = fmaxf(a2 * dv + bA.z, 0.0f); w0.w = fmaxf(a3 * dv + bA.w, 0.0f);
        w1.x = fmaxf(a4 * dv + bB.x, 0.0f); w1.y = fmaxf(a5 * dv + bB.y, 0.0f);
        w1.z = fmaxf(a6 * dv + bB.z, 0.0f); w1.w = fmaxf(a7 * dv + bB.w, 0.0f);
        *(float4*)&sH[wvl * 8 + sub][frag * 8] = w0;
        *(float4*)&sH[wvl * 8 + sub][frag * 8 + 4] = w1;
    }
    __syncthreads();
    // block epilogue: xs8_2[32 nodes x 64] = fp8(sH @ W2)  (unscaled)
    int r = threadIdx.x >> 3;
    int cg = (threadIdx.x & 7) * 8;
    float b0 = 0, b1 = 0, b2 = 0, b3 = 0, b4 = 0, b5 = 0, b6 = 0, b7 = 0;
#pragma unroll 8
    for (int k = 0; k < 64; ++k) {
        float hv = sH[r][k];
        float4 wa = *(const float4*)&sW2[k * 64 + cg];
        float4 wbv = *(const float4*)&sW2[k * 64 + cg + 4];
        b0 += hv * wa.x; b1 += hv * wa.y; b2 += hv * wa.z; b3 += hv * wa.w;
        b4 += hv * wbv.x; b5 += hv * wbv.y; b6 += hv * wbv.z; b7 += hv * wbv.w;
    }
    int node2 = blockIdx.x * 32 + r;
    if (node2 < N_NODES) {
        unsigned int p0 = 0, p1 = 0;
        p0 = __builtin_amdgcn_cvt_pk_fp8_f32(b0, b1, p0, false);
        p0 = __builtin_amdgcn_cvt_pk_fp8_f32(b2, b3, p0, true);
        p1 = __builtin_amdgcn_cvt_pk_fp8_f32(b4, b5, p1, false);
        p1 = __builtin_amdgcn_cvt_pk_fp8_f32(b6, b7, p1, true);
        *(uint2*)(xs8o + node2 * 16 + (cg >> 2)) = make_uint2(p0, p1);
    }
}

// ---- gather layer 2 (per-src dinv fma): writes h2 as fp16 ----
__global__ __launch_bounds__(256) void gather_h2(const unsigned char* __restrict__ xs8,
                                                 const int2* __restrict__ ggrp,
                                                 const int* __restrict__ sorted,
                                                 const float* __restrict__ dinv,
                                                 const float* __restrict__ bias,
                                                 __half* __restrict__ h2) {
    int grp = blockIdx.x * 4 + (threadIdx.x >> 6);
    int lane = threadIdx.x & 63;
    int sub = lane >> 3, frag = lane & 7;
    int node = grp * 8 + sub;
    int2 gi = ggrp[grp];
    int K = gi.y;
    const int* sp = sorted + gi.x + sub;
    const uint2* xr = (const uint2*)xs8 + frag;
    float a0 = 0, a1 = 0, a2 = 0, a3 = 0, a4 = 0, a5 = 0, a6 = 0, a7 = 0;
    int i0 = sp[0], i1 = sp[8], i2 = sp[16], i3 = sp[24];
    for (int k = 0; k < K; k += 4) {
        uint2 r0 = xr[i0 * 8];
        uint2 r1 = xr[i1 * 8];
        uint2 r2 = xr[i2 * 8];
        uint2 r3 = xr[i3 * 8];
        float s0 = dinv[i0], s1 = dinv[i1], s2 = dinv[i2], s3 = dinv[i3];
        const int* np = sp + (k + 4) * 8;
        i0 = np[0]; i1 = np[8]; i2 = np[16]; i3 = np[24];
        FMA_ROW(r0, s0); FMA_ROW(r1, s1); FMA_ROW(r2, s2); FMA_ROW(r3, s3);
    }
    if (node < N_NODES) {
        float dv = dinv[node];
        float4 bA = *(const float4*)(bias + frag * 8);
        float4 bB = *(const float4*)(bias + frag * 8 + 4);
        float v0 = fmaxf(a0 * dv + bA.x, 0.0f), v1 = fmaxf(a1 * dv + bA.y, 0.0f);
        float v2 = fmaxf(a2 * dv + bA.z, 0.0f), v3 = fmaxf(a3 * dv + bA.w, 0.0f);
        float v4 = fmaxf(a4 * dv + bB.x, 0.0f), v5 = fmaxf(a5 * dv + bB.y, 0.0f);
        float v6 = fmaxf(a6 * dv + bB.z, 0.0f), v7 = fmaxf(a7 * dv + bB.w, 0.0f);
        __half2 p0 = __floats2half2_rn(v0, v1), p1 = __floats2half2_rn(v2, v3);
        __half2 p2 = __floats2half2_rn(v4, v5), p3 = __floats2half2_rn(v6, v7);
        uint4 pk;
        pk.x = *(unsigned int*)&p0; pk.y = *(unsigned int*)&p1;
        pk.z = *(unsigned int*)&p2; pk.w = *(unsigned int*)&p3;
        *(uint4*)(h2 + node * 64 + frag * 8) = pk;
    }
}

// ---- fused pool (segmented mean, precomputed boundaries) + fc head + log_softmax ----
__global__ __launch_bounds__(256) void pool_head(const __half* __restrict__ h2,
                                                 const int* __restrict__ gbound,
                                                 const float* __restrict__ Wfc, const float* __restrict__ bfc,
                                                 const int* __restrict__ y, float* __restrict__ out) {
    __shared__ float sh[4][64];
    __shared__ float pl[64];
    __shared__ float lg[4];
    int g = blockIdx.x;
    int t = threadIdx.x;
    int beg = gbound[g], end = gbound[g + 1];
    int f = t & 63, seg = t >> 6;
    float s = 0.0f;
    for (int r = beg + seg; r < end; r += 4) s += __half2float(h2[r * 64 + f]);
    sh[seg][f] = s;
    __syncthreads();
    if (t < 64) {
        float p = sh[0][t] + sh[1][t] + sh[2][t] + sh[3][t];
        pl[t] = p / fmaxf((float)(end - beg), 1.0f);
    }
    __syncthreads();
    if (t < 4) {
        float l = bfc[t];
#pragma unroll
        for (int k = 0; k < 64; ++k) l += pl[k] * Wfc[k * 4 + t];
        lg[t] = l;
    }
    __syncthreads();
    if (t == 0) {
        float l0 = lg[0], l1 = lg[1], l2 = lg[2], l3 = lg[3];
        float m = fmaxf(fmaxf(l0, l1), fmaxf(l2, l3));
        float ss = expf(l0 - m) + expf(l1 - m) + expf(l2 - m) + expf(l3 - m);
        float lse = m + logf(ss);
        out[g * 4 + 0] = l0 - lse;
        out[g * 4 + 1] = l1 - lse;
        out[g * 4 + 2] = l2 - lse;
        out[g * 4 + 3] = l3 - lse;
        out[N_GRAPHS * 4 + g] = (float)y[g];
    }
}

extern "C" void kernel_launch(void* const* d_in, const int* in_sizes, int n_in,
                              void* d_out, int out_size, void* d_ws, size_t ws_size,
                              hipStream_t stream) {
    const float* x     = (const float*)d_in[0];
    const int*   ei    = (const int*)d_in[1];
    const int*   batch = (const int*)d_in[2];
    const int*   y     = (const int*)d_in[3];
    const float* W1    = (const float*)d_in[4];
    const float* b1    = (const float*)d_in[5];
    const float* W2    = (const float*)d_in[6];
    const float* b2    = (const float*)d_in[7];
    const float* Wfc   = (const float*)d_in[8];
    const float* bfc   = (const float*)d_in[9];
    float* out = (float*)d_out;

    const int* src = ei;
    const int* dst = ei + N_EDGES;

    char* wsb = (char*)d_ws;
    float*        dinv   = (float*)(wsb + OFF_DINV);
    int2*         ggrp   = (int2*)(wsb + OFF_GGRP);
    int*          cntmat = (int*)(wsb + OFF_CNTM);
    int*          gbound = (int*)(wsb + OFF_GB);
    unsigned int* tmp    = (unsigned int*)(wsb + OFF_TMP);
    int*          sorted = (int*)(wsb + OFF_SORTED);
    unsigned int* xs8_1  = (unsigned int*)(wsb + OFF_XS8_1);
    unsigned int* xs8_2  = (unsigned int*)(wsb + OFF_XS8_2);
    __half*       h2     = (__half*)(wsb + OFF_H2);

    binA<<<NSEG, 256, 0, stream>>>(src, dst, batch, cntmat, tmp, xs8_1, xs8_2, dinv, gbound);
    // binB2 (half-buckets, streamed passes) + gemm1 (bf16 MFMA) run concurrently
    prep<<<PREP_GRID, 256, 0, stream>>>(tmp, cntmat, sorted, ggrp, dinv, x, W1, xs8_1);
    // layer-1 aggregate (per-src dinv fma) + relu + fused W2 GEMM -> xs8_2
    gather_fuse<<<NBLK_G, 256, 0, stream>>>((const unsigned char*)xs8_1, ggrp, sorted,
                                            dinv, b1, W2, xs8_2);
    // layer-2 aggregate + relu -> h2 (fp16)
    gather_h2<<<NBLK_G, 256, 0, stream>>>((const unsigned char*)xs8_2, ggrp, sorted,
                                          dinv, b2, h2);
    pool_head<<<N_GRAPHS, 256, 0, stream>>>(h2, gbound, Wfc, bfc, y, out);
}

// Round 8
// 166.058 us; speedup vs baseline: 1.3027x; 1.3027x over previous
//
#include <hip/hip_runtime.h>
#include <hip/hip_fp16.h>
#include <math.h>

#define N_NODES 50000
#define N_EDGES 800000
#define N_GRAPHS 512
#define NBKT 196                          // 256-node buckets
#define SENT N_NODES
#define EPB 2048                          // edges per binA block
#define NSEG 391                          // ceil(800000/2048)
#define CAP_C 48                          // slots per (bucket,segment) run; max observed ~30
#define NBLK_B2 392                       // half-bucket blocks (128 nodes each)
#define CAP_SH 8192                       // sorted ints per half-bucket (worst-case sum < 6700)
#define NBLK_GM 782                       // gemm blocks (64 rows each)
#define PREP_GRID (NBLK_B2 + NBLK_GM)     // 1174
#define N_GROUPS 6272                     // 392*16 groups of 8 nodes
#define NBLK_G 1568                       // 6272/4 gather blocks

typedef float v2f __attribute__((ext_vector_type(2)));
typedef float f32x4 __attribute__((ext_vector_type(4)));
typedef short s16x8 __attribute__((ext_vector_type(8)));

// workspace byte offsets (256B-aligned)
#define OFF_DINV    0u                    // 50176 floats (nodes + sentinel + pad)
#define OFF_GGRP    200704u               // 6272 int2 {slot base, K loop bound}
#define OFF_CNTM    250880u               // 391*196 ints
#define OFF_TMP     557568u               // 196*391*48 uints = 14,714,112 B
#define OFF_SORTED  15271680u             // 392*8192 ints = 12,845,056 B
#define OFF_XS8_1   28116736u             // 50001*64 B fp8 (unscaled)
#define OFF_XS8_2   31316992u             // 50001*64 B fp8 (unscaled)
#define OFF_H2      34517248u             // 50000*64 fp16
#define OFF_GB      40917248u             // 513 ints (graph boundaries)

__device__ __forceinline__ unsigned short f2bf(float f) {   // fp32 -> bf16 bits, RNE
    unsigned int u = __float_as_uint(f);
    u += 0x7FFFu + ((u >> 16) & 1u);
    return (unsigned short)(u >> 16);
}

// ---- binA: fixed-slot binning + graph-boundary precompute; no global atomics ----
__global__ __launch_bounds__(256) void binA(const int* __restrict__ src, const int* __restrict__ dst,
                                            const int* __restrict__ batch,
                                            int* __restrict__ cntmat, unsigned int* __restrict__ tmp,
                                            unsigned int* __restrict__ x1, unsigned int* __restrict__ x2,
                                            float* __restrict__ dinv, int* __restrict__ gbound) {
    __shared__ int cnt[256];
    int t = threadIdx.x;
    cnt[t] = 0;
    if (blockIdx.x == 0) {                 // zero fp8 sentinel rows + dinv sentinel
        if (t < 16) x1[N_NODES * 16 + t] = 0;
        else if (t < 32) x2[N_NODES * 16 + (t - 16)] = 0;
        else if (t == 32) dinv[SENT] = 0.0f;
    }
    if (blockIdx.x < 25) {                 // gbound[g] = first node idx with batch >= g
        int i0 = blockIdx.x * 2048;
#pragma unroll
        for (int it = 0; it < 8; ++it) {
            int i = i0 + it * 256 + t;
            if (i < N_NODES) {
                int b0 = batch[i];
                int b1 = (i + 1 < N_NODES) ? batch[i + 1] : N_GRAPHS;
                for (int g = b0 + 1; g <= b1; ++g) gbound[g] = i + 1;
                if (i == 0)
                    for (int g = 0; g <= b0; ++g) gbound[g] = 0;
            }
        }
    }
    __syncthreads();
    int e0 = blockIdx.x * EPB;
#pragma unroll
    for (int i = 0; i < 8; ++i) {
        int e = e0 + i * 256 + t;
        if (e < N_EDGES) {
            int s = src[e], d = dst[e];
            int b = d >> 8;
            int p = atomicAdd(&cnt[b], 1);
            tmp[(b * NSEG + blockIdx.x) * CAP_C + p] =
                (unsigned int)s | ((unsigned int)(d & 255) << 17);   // src < 2^17
        }
    }
    __syncthreads();
    if (t < NBKT) cntmat[blockIdx.x * NBKT + t] = cnt[t];
}

// ---- prep: heterogeneous grid. blocks [0,392): binB2 half-bucket CSR build.
//      blocks [392,1174): bf16-MFMA gemm1 (xs8_1 = fp8(X @ W1), UNSCALED). ----
__global__ __launch_bounds__(256) void prep(const unsigned int* __restrict__ tmp,
                                            const int* __restrict__ cntmat,
                                            int* __restrict__ sorted, int2* __restrict__ ggrp,
                                            float* __restrict__ dinv,
                                            const float* __restrict__ X, const float* __restrict__ W1,
                                            unsigned int* __restrict__ xs8) {
    __shared__ __align__(16) char pool[34816];
    int t = threadIdx.x;

    if (blockIdx.x < NBLK_B2) {
        // ---------------- binB2 half-bucket (per-segment passes, R2-proven) ----------------
        int* cnt  = (int*)pool;              // 128
        int* lbs  = (int*)(pool + 512);      // 128
        int* cur  = (int*)(pool + 1024);     // 128
        int* gK   = (int*)(pool + 1536);     // 16
        int* gpre = (int*)(pool + 1600);     // 17
        int* ldsS = (int*)(pool + 1792);     // 8192 ints
        int b2 = blockIdx.x, bkt = b2 >> 1, half = b2 & 1;
        if (t < 128) cnt[t] = 0;
        __syncthreads();
        // pass A: count degrees of my 128 nodes across 391 segments
        for (int seg = t; seg < NSEG; seg += 256) {
            int c = cntmat[seg * NBKT + bkt];
            const unsigned int* tp = tmp + (bkt * NSEG + seg) * CAP_C;
            for (int e = 0; e < c; ++e) {
                int d = (int)(tp[e] >> 17);
                if ((d >> 7) == half) atomicAdd(&cnt[d & 127], 1);
            }
        }
        __syncthreads();
        int node = 0, deg = 0, K = 0, KP = 0, lb = 0, myreal = 0;
        if (t < 128) {
            node = bkt * 256 + half * 128 + t;
            myreal = node < N_NODES;
            deg = cnt[t];
            int count = myreal ? deg + 1 : 0;        // +1 self loop
            int mx = count;
            mx = max(mx, __shfl_xor(mx, 1));
            mx = max(mx, __shfl_xor(mx, 2));
            mx = max(mx, __shfl_xor(mx, 4));
            K = (mx + 3) & ~3;                       // group loop bound (mult of 4)
            KP = K + 4;                              // +extra quad: guard-free prefetch
            if ((t & 7) == 0) gK[t >> 3] = KP;
        }
        __syncthreads();
        if (t == 0) {
            int s = 0;
#pragma unroll
            for (int g = 0; g < 16; ++g) { gpre[g] = s; s += gK[g]; }
            gpre[16] = s;
        }
        __syncthreads();
        if (t < 128) {
            lb = 8 * gpre[t >> 3] + (t & 7);
            lbs[t] = lb;
            cur[t] = myreal ? 1 : 0;
            if (myreal) {
                dinv[node] = rsqrtf(1.0f + (float)deg);
                ldsS[lb] = node;                     // self loop at entry 0
            }
            if ((t & 7) == 0)
                ggrp[b2 * 16 + (t >> 3)] = make_int2(b2 * CAP_SH + 8 * gpre[t >> 3], K);
        }
        __syncthreads();
        // pass B: scatter my edges
        for (int seg = t; seg < NSEG; seg += 256) {
            int c = cntmat[seg * NBKT + bkt];
            const unsigned int* tp = tmp + (bkt * NSEG + seg) * CAP_C;
            for (int e = 0; e < c; ++e) {
                unsigned int pk = tp[e];
                int d = (int)(pk >> 17);
                if ((d >> 7) == half) {
                    int loc = d & 127;
                    int j = atomicAdd(&cur[loc], 1);
                    ldsS[lbs[loc] + j * 8] = (int)(pk & 0x1FFFFu);
                }
            }
        }
        __syncthreads();
        if (t < 128)
            for (int j = cur[t]; j < KP; ++j) ldsS[lb + j * 8] = SENT;
        __syncthreads();
        int ptot = 8 * gpre[16];
        int4* dst4 = (int4*)(sorted + b2 * CAP_SH);
        const int4* src4 = (const int4*)ldsS;
        for (int p = t; p < (ptot >> 2); p += 256) dst4[p] = src4[p];
    } else {
        // ---- gemm1: 64 rows/block, mfma_f32_16x16x32_bf16 (HW-verified r2-r7) ----
        short* W1T = (short*)pool;               // [64 cols][136] bf16 bits
        float* sD  = (float*)(pool + 17408);     // [64 rows][68]
        int gb = blockIdx.x - NBLK_B2;
        int row0 = gb * 64;
        for (int i = t; i < 8192; i += 256) {    // stage W1 transposed to bf16
            int k = i >> 6, c = i & 63;
            W1T[c * 136 + k] = (short)f2bf(W1[i]);
        }
        __syncthreads();
        int w = t >> 6, lane = t & 63;
        int arow = lane & 15, kg = lane >> 4;    // arow = A-row = B-col; kg = k-group
        int r = row0 + w * 16 + arow;
        const float* xp = X + r * 128 + kg * 8;
        bool vr = (r < N_NODES);
        const short* wb = &W1T[arow * 136 + kg * 8];
        f32x4 ac0 = {0.f, 0.f, 0.f, 0.f}, ac1 = ac0, ac2 = ac0, ac3 = ac0;
#pragma unroll
        for (int kk = 0; kk < 4; ++kk) {
            float4 xa, xb;
            if (vr) { xa = *(const float4*)(xp); xb = *(const float4*)(xp + 4); }
            else    { xa = make_float4(0.f, 0.f, 0.f, 0.f); xb = xa; }
            xp += 32;
            s16x8 af;
            af[0] = (short)f2bf(xa.x); af[1] = (short)f2bf(xa.y);
            af[2] = (short)f2bf(xa.z); af[3] = (short)f2bf(xa.w);
            af[4] = (short)f2bf(xb.x); af[5] = (short)f2bf(xb.y);
            af[6] = (short)f2bf(xb.z); af[7] = (short)f2bf(xb.w);
            const short* wk = wb + kk * 32;
            s16x8 bf0 = *(const s16x8*)(wk);
            s16x8 bf1 = *(const s16x8*)(wk + 16 * 136);
            s16x8 bf2 = *(const s16x8*)(wk + 32 * 136);
            s16x8 bf3 = *(const s16x8*)(wk + 48 * 136);
            asm volatile(
                "s_nop 1\n\t"
                "v_mfma_f32_16x16x32_bf16 %0, %4, %5, %0\n\t"
                "v_mfma_f32_16x16x32_bf16 %1, %4, %6, %1\n\t"
                "v_mfma_f32_16x16x32_bf16 %2, %4, %7, %2\n\t"
                "v_mfma_f32_16x16x32_bf16 %3, %4, %8, %3"
                : "+v"(ac0), "+v"(ac1), "+v"(ac2), "+v"(ac3)
                : "v"(af), "v"(bf0), "v"(bf1), "v"(bf2), "v"(bf3));
        }
        asm volatile("s_nop 7\n\ts_nop 7");      // MFMA->VALU read hazard pad
        int dr = w * 16 + kg * 4;                // D row = (lane>>4)*4+reg; col = lane&15
#pragma unroll
        for (int reg = 0; reg < 4; ++reg) {
            sD[(dr + reg) * 68 + arow]      = ac0[reg];
            sD[(dr + reg) * 68 + 16 + arow] = ac1[reg];
            sD[(dr + reg) * 68 + 32 + arow] = ac2[reg];
            sD[(dr + reg) * 68 + 48 + arow] = ac3[reg];
        }
        __syncthreads();
        for (int i = t; i < 1024; i += 256) {    // quantize fp8 (unscaled)
            int lr = i >> 4, q = i & 15;
            int nd = row0 + lr;
            if (nd < N_NODES) {
                float4 v = *(const float4*)&sD[lr * 68 + q * 4];
                unsigned int pk = 0;
                pk = __builtin_amdgcn_cvt_pk_fp8_f32(v.x, v.y, pk, false);
                pk = __builtin_amdgcn_cvt_pk_fp8_f32(v.z, v.w, pk, true);
                xs8[nd * 16 + q] = pk;
            }
        }
    }
}

// ---- fp8-row accumulate with per-source dinv scale (unscaled input) ----
#define FMA_ROW(rv, ds) { \
    v2f f0 = __builtin_amdgcn_cvt_pk_f32_fp8((rv).x, false); \
    v2f f1 = __builtin_amdgcn_cvt_pk_f32_fp8((rv).x, true); \
    v2f f2 = __builtin_amdgcn_cvt_pk_f32_fp8((rv).y, false); \
    v2f f3 = __builtin_amdgcn_cvt_pk_f32_fp8((rv).y, true); \
    a0 += f0.x * (ds); a1 += f0.y * (ds); a2 += f1.x * (ds); a3 += f1.y * (ds); \
    a4 += f2.x * (ds); a5 += f2.y * (ds); a6 += f3.x * (ds); a7 += f3.y * (ds); }

// ---- gather layer 1 + fused W2 GEMM; epilogue emits xs8_2 (unscaled) ----
__global__ __launch_bounds__(256) void gather_fuse(const unsigned char* __restrict__ xs8,
                                                   const int2* __restrict__ ggrp,
                                                   const int* __restrict__ sorted,
                                                   const float* __restrict__ dinv,
                                                   const float* __restrict__ bias,
                                                   const float* __restrict__ W2,
                                                   unsigned int* __restrict__ xs8o) {
    __shared__ float sW2[64 * 64];
    __shared__ float sH[32][68];
    {
        const float4* ws = (const float4*)W2;
        float4* wd = (float4*)sW2;
        for (int i = threadIdx.x; i < 1024; i += 256) wd[i] = ws[i];
    }
    int wvl = threadIdx.x >> 6;
    int grp = blockIdx.x * 4 + wvl;

    int lane = threadIdx.x & 63;
    int sub = lane >> 3, frag = lane & 7;
    int node = grp * 8 + sub;
    int2 gi = ggrp[grp];
    int K = gi.y;
    const int* sp = sorted + gi.x + sub;
    const uint2* xr = (const uint2*)xs8 + frag;
    float a0 = 0, a1 = 0, a2 = 0, a3 = 0, a4 = 0, a5 = 0, a6 = 0, a7 = 0;
    int i0 = sp[0], i1 = sp[8], i2 = sp[16], i3 = sp[24];
    for (int k = 0; k < K; k += 4) {
        uint2 r0 = xr[i0 * 8];
        uint2 r1 = xr[i1 * 8];
        uint2 r2 = xr[i2 * 8];
        uint2 r3 = xr[i3 * 8];
        float s0 = dinv[i0], s1 = dinv[i1], s2 = dinv[i2], s3 = dinv[i3];
        const int* np = sp + (k + 4) * 8;
        i0 = np[0]; i1 = np[8]; i2 = np[16]; i3 = np[24];
        FMA_ROW(r0, s0); FMA_ROW(r1, s1); FMA_ROW(r2, s2); FMA_ROW(r3, s3);
    }
    {
        float dv = dinv[node];
        float4 bA = *(const float4*)(bias + frag * 8);
        float4 bB = *(const float4*)(bias + frag * 8 + 4);
        float4 w0, w1;
        w0.x = fmaxf(a0 * dv + bA.x, 0.0f); w0.y = fmaxf(a1 * dv + bA.y, 0.0f);
        w0.z = fmaxf(a2 * dv + bA.z, 0.0f); w0.w = fmaxf(a3 * dv + bA.w, 0.0f);
        w1.x = fmaxf(a4 * dv + bB.x, 0.0f); w1.y = fmaxf(a5 * dv + bB.y, 0.0f);
        w1.z = fmaxf(a6 * dv + bB.z, 0.0f); w1.w = fmaxf(a7 * dv + bB.w, 0.0f);
        *(float4*)&sH[wvl * 8 + sub][frag * 8] = w0;
        *(float4*)&sH[wvl * 8 + sub][frag * 8 + 4] = w1;
    }
    __syncthreads();
    // block epilogue: xs8_2[32 nodes x 64] = fp8(sH @ W2)  (unscaled)
    int r = threadIdx.x >> 3;
    int cg = (threadIdx.x & 7) * 8;
    float b0 = 0, b1 = 0, b2 = 0, b3 = 0, b4 = 0, b5 = 0, b6 = 0, b7 = 0;
#pragma unroll 8
    for (int k = 0; k < 64; ++k) {
        float hv = sH[r][k];
        float4 wa = *(const float4*)&sW2[k * 64 + cg];
        float4 wbv = *(const float4*)&sW2[k * 64 + cg + 4];
        b0 += hv * wa.x; b1 += hv * wa.y; b2 += hv * wa.z; b3 += hv * wa.w;
        b4 += hv * wbv.x; b5 += hv * wbv.y; b6 += hv * wbv.z; b7 += hv * wbv.w;
    }
    int node2 = blockIdx.x * 32 + r;
    if (node2 < N_NODES) {
        unsigned int p0 = 0, p1 = 0;
        p0 = __builtin_amdgcn_cvt_pk_fp8_f32(b0, b1, p0, false);
        p0 = __builtin_amdgcn_cvt_pk_fp8_f32(b2, b3, p0, true);
        p1 = __builtin_amdgcn_cvt_pk_fp8_f32(b4, b5, p1, false);
        p1 = __builtin_amdgcn_cvt_pk_fp8_f32(b6, b7, p1, true);
        *(uint2*)(xs8o + node2 * 16 + (cg >> 2)) = make_uint2(p0, p1);
    }
}

// ---- gather layer 2 (per-src dinv fma): writes h2 as fp16 ----
__global__ __launch_bounds__(256) void gather_h2(const unsigned char* __restrict__ xs8,
                                                 const int2* __restrict__ ggrp,
                                                 const int* __restrict__ sorted,
                                                 const float* __restrict__ dinv,
                                                 const float* __restrict__ bias,
                                                 __half* __restrict__ h2) {
    int grp = blockIdx.x * 4 + (threadIdx.x >> 6);
    int lane = threadIdx.x & 63;
    int sub = lane >> 3, frag = lane & 7;
    int node = grp * 8 + sub;
    int2 gi = ggrp[grp];
    int K = gi.y;
    const int* sp = sorted + gi.x + sub;
    const uint2* xr = (const uint2*)xs8 + frag;
    float a0 = 0, a1 = 0, a2 = 0, a3 = 0, a4 = 0, a5 = 0, a6 = 0, a7 = 0;
    int i0 = sp[0], i1 = sp[8], i2 = sp[16], i3 = sp[24];
    for (int k = 0; k < K; k += 4) {
        uint2 r0 = xr[i0 * 8];
        uint2 r1 = xr[i1 * 8];
        uint2 r2 = xr[i2 * 8];
        uint2 r3 = xr[i3 * 8];
        float s0 = dinv[i0], s1 = dinv[i1], s2 = dinv[i2], s3 = dinv[i3];
        const int* np = sp + (k + 4) * 8;
        i0 = np[0]; i1 = np[8]; i2 = np[16]; i3 = np[24];
        FMA_ROW(r0, s0); FMA_ROW(r1, s1); FMA_ROW(r2, s2); FMA_ROW(r3, s3);
    }
    if (node < N_NODES) {
        float dv = dinv[node];
        float4 bA = *(const float4*)(bias + frag * 8);
        float4 bB = *(const float4*)(bias + frag * 8 + 4);
        float v0 = fmaxf(a0 * dv + bA.x, 0.0f), v1 = fmaxf(a1 * dv + bA.y, 0.0f);
        float v2 = fmaxf(a2 * dv + bA.z, 0.0f), v3 = fmaxf(a3 * dv + bA.w, 0.0f);
        float v4 = fmaxf(a4 * dv + bB.x, 0.0f), v5 = fmaxf(a5 * dv + bB.y, 0.0f);
        float v6 = fmaxf(a6 * dv + bB.z, 0.0f), v7 = fmaxf(a7 * dv + bB.w, 0.0f);
        __half2 p0 = __floats2half2_rn(v0, v1), p1 = __floats2half2_rn(v2, v3);
        __half2 p2 = __floats2half2_rn(v4, v5), p3 = __floats2half2_rn(v6, v7);
        uint4 pk;
        pk.x = *(unsigned int*)&p0; pk.y = *(unsigned int*)&p1;
        pk.z = *(unsigned int*)&p2; pk.w = *(unsigned int*)&p3;
        *(uint4*)(h2 + node * 64 + frag * 8) = pk;
    }
}

// ---- fused pool (segmented mean, precomputed boundaries) + fc head + log_softmax ----
__global__ __launch_bounds__(256) void pool_head(const __half* __restrict__ h2,
                                                 const int* __restrict__ gbound,
                                                 const float* __restrict__ Wfc, const float* __restrict__ bfc,
                                                 const int* __restrict__ y, float* __restrict__ out) {
    __shared__ float sh[4][64];
    __shared__ float pl[64];
    __shared__ float lg[4];
    int g = blockIdx.x;
    int t = threadIdx.x;
    int beg = gbound[g], end = gbound[g + 1];
    int f = t & 63, seg = t >> 6;
    float s = 0.0f;
    for (int r = beg + seg; r < end; r += 4) s += __half2float(h2[r * 64 + f]);
    sh[seg][f] = s;
    __syncthreads();
    if (t < 64) {
        float p = sh[0][t] + sh[1][t] + sh[2][t] + sh[3][t];
        pl[t] = p / fmaxf((float)(end - beg), 1.0f);
    }
    __syncthreads();
    if (t < 4) {
        float l = bfc[t];
#pragma unroll
        for (int k = 0; k < 64; ++k) l += pl[k] * Wfc[k * 4 + t];
        lg[t] = l;
    }
    __syncthreads();
    if (t == 0) {
        float l0 = lg[0], l1 = lg[1], l2 = lg[2], l3 = lg[3];
        float m = fmaxf(fmaxf(l0, l1), fmaxf(l2, l3));
        float ss = expf(l0 - m) + expf(l1 - m) + expf(l2 - m) + expf(l3 - m);
        float lse = m + logf(ss);
        out[g * 4 + 0] = l0 - lse;
        out[g * 4 + 1] = l1 - lse;
        out[g * 4 + 2] = l2 - lse;
        out[g * 4 + 3] = l3 - lse;
        out[N_GRAPHS * 4 + g] = (float)y[g];
    }
}

extern "C" void kernel_launch(void* const* d_in, const int* in_sizes, int n_in,
                              void* d_out, int out_size, void* d_ws, size_t ws_size,
                              hipStream_t stream) {
    const float* x     = (const float*)d_in[0];
    const int*   ei    = (const int*)d_in[1];
    const int*   batch = (const int*)d_in[2];
    const int*   y     = (const int*)d_in[3];
    const float* W1    = (const float*)d_in[4];
    const float* b1    = (const float*)d_in[5];
    const float* W2    = (const float*)d_in[6];
    const float* b2    = (const float*)d_in[7];
    const float* Wfc   = (const float*)d_in[8];
    const float* bfc   = (const float*)d_in[9];
    float* out = (float*)d_out;

    const int* src = ei;
    const int* dst = ei + N_EDGES;

    char* wsb = (char*)d_ws;
    float*        dinv   = (float*)(wsb + OFF_DINV);
    int2*         ggrp   = (int2*)(wsb + OFF_GGRP);
    int*          cntmat = (int*)(wsb + OFF_CNTM);
    unsigned int* tmp    = (unsigned int*)(wsb + OFF_TMP);
    int*          sorted = (int*)(wsb + OFF_SORTED);
    unsigned int* xs8_1  = (unsigned int*)(wsb + OFF_XS8_1);
    unsigned int* xs8_2  = (unsigned int*)(wsb + OFF_XS8_2);
    __half*       h2     = (__half*)(wsb + OFF_H2);
    int*          gbound = (int*)(wsb + OFF_GB);

    binA<<<NSEG, 256, 0, stream>>>(src, dst, batch, cntmat, tmp, xs8_1, xs8_2, dinv, gbound);
    // binB2 (half-buckets, per-segment passes) + gemm1 (bf16 MFMA) run concurrently
    prep<<<PREP_GRID, 256, 0, stream>>>(tmp, cntmat, sorted, ggrp, dinv, x, W1, xs8_1);
    // layer-1 aggregate (per-src dinv fma) + relu + fused W2 GEMM -> xs8_2
    gather_fuse<<<NBLK_G, 256, 0, stream>>>((const unsigned char*)xs8_1, ggrp, sorted,
                                            dinv, b1, W2, xs8_2);
    // layer-2 aggregate + relu -> h2 (fp16)
    gather_h2<<<NBLK_G, 256, 0, stream>>>((const unsigned char*)xs8_2, ggrp, sorted,
                                          dinv, b2, h2);
    pool_head<<<N_GRAPHS, 256, 0, stream>>>(h2, gbound, Wfc, bfc, y, out);
}